// Round 3
// baseline (269.120 us; speedup 1.0000x reference)
//
#include <hip/hip_runtime.h>

typedef unsigned short u16;
typedef __bf16 bf16_t;
typedef bf16_t bf16x8 __attribute__((ext_vector_type(8)));
typedef float f32x4 __attribute__((ext_vector_type(4)));
typedef u16 u16x8 __attribute__((ext_vector_type(8)));

#define B_ 8
#define S_ 4096
#define H_ 768
#define M_ (B_ * S_)

// round-to-nearest-even fp32 -> bf16
__device__ __forceinline__ u16 f2b(float f) {
  unsigned u = __float_as_uint(f);
  u += 0x7fffu + ((u >> 16) & 1u);
  return (u16)(u >> 16);
}

// ---------------------------------------------------------------------------
// Kernel 1: WbT[n][k] bf16 (n: 0-63=q,64-127=k,128-191=v). Coalesced.
// ---------------------------------------------------------------------------
__global__ __launch_bounds__(256) void wconv_k(const float* __restrict__ Wq,
                                               const float* __restrict__ Wk,
                                               const float* __restrict__ Wv,
                                               u16* __restrict__ WbT) {
  __shared__ float wt[64 * 68];
  const int tid = threadIdx.x;
  int mat = blockIdx.x / 12;
  int k0 = (blockIdx.x % 12) * 64;
  const float* W = (mat == 0) ? Wq : ((mat == 1) ? Wk : Wv);
  int r = tid >> 2, c0 = (tid & 3) * 16;
  const float* src = W + (size_t)(k0 + r) * 64 + c0;
#pragma unroll
  for (int j = 0; j < 16; j += 4)
    *(float4*)&wt[r * 68 + c0 + j] = *(const float4*)(src + j);
  __syncthreads();
  int d = tid >> 2;
  u16* dst = WbT + (size_t)(mat * 64 + d) * 768 + k0 + c0;
  u16x8 o0, o1;
#pragma unroll
  for (int j = 0; j < 8; ++j) o0[j] = f2b(wt[(c0 + j) * 68 + d]);
#pragma unroll
  for (int j = 0; j < 8; ++j) o1[j] = f2b(wt[(c0 + 8 + j) * 68 + d]);
  *(u16x8*)dst = o0;
  *(u16x8*)(dst + 8) = o1;
}

// ---------------------------------------------------------------------------
// Kernel 2: QKV projection. 1 barrier/iter double-buffer (reg prefetch).
// q pre-scaled by 0.125*log2(e). q,k stored [s][d]; V stored [b][d][s].
// ---------------------------------------------------------------------------
__global__ __launch_bounds__(256) void qkv_k(const float* __restrict__ x,
                                             const u16* __restrict__ WbT,
                                             const float* __restrict__ bq,
                                             const float* __restrict__ bk,
                                             const float* __restrict__ bv,
                                             u16* __restrict__ qb,
                                             u16* __restrict__ kb,
                                             u16* __restrict__ vbT) {
  __shared__ __align__(16) u16 smem[2 * 2560 + 2 * 7680];  // xs[2], ws[2]
  const int tid = threadIdx.x;
  const int w = tid >> 6, ln = tid & 15, qd = (tid >> 4) & 3;
  const int row0 = blockIdx.x * 64;

  const f32x4 z4 = {0.f, 0.f, 0.f, 0.f};
  f32x4 acc[4][3];
#pragma unroll
  for (int rt = 0; rt < 4; ++rt)
#pragma unroll
    for (int ct = 0; ct < 3; ++ct) acc[rt][ct] = z4;

  const int xr = tid >> 2, xc = (tid & 3) * 8;
  float4 xf0, xf1;
  u16x8 wf[3];

  auto load_t = [&](int kt) {
    const float* sx = x + (size_t)(row0 + xr) * 768 + kt * 32 + xc;
    xf0 = *(const float4*)sx;
    xf1 = *(const float4*)(sx + 4);
#pragma unroll
    for (int i = 0; i < 3; ++i) {
      int c = i * 256 + tid;
      int r = c >> 2, off = (c & 3) * 8;
      wf[i] = *(const u16x8*)(WbT + (size_t)r * 768 + kt * 32 + off);
    }
  };
  auto write_b = [&](int kt) {
    u16* xs = smem + (kt & 1) * 2560;
    u16* wsb = smem + 5120 + (kt & 1) * 7680;
    u16x8 v;
    v[0] = f2b(xf0.x); v[1] = f2b(xf0.y); v[2] = f2b(xf0.z); v[3] = f2b(xf0.w);
    v[4] = f2b(xf1.x); v[5] = f2b(xf1.y); v[6] = f2b(xf1.z); v[7] = f2b(xf1.w);
    *(u16x8*)&xs[xr * 40 + xc] = v;
#pragma unroll
    for (int i = 0; i < 3; ++i) {
      int c = i * 256 + tid;
      int r = c >> 2, off = (c & 3) * 8;
      *(u16x8*)&wsb[r * 40 + off] = wf[i];
    }
  };

  load_t(0);
  write_b(0);
  load_t(1);
  for (int kt = 0; kt < 24; ++kt) {
    __syncthreads();  // buf(kt) visible to all waves
    if (kt < 23) {
      write_b(kt + 1);           // other buffer; safe (read-done pre-barrier)
      if (kt < 22) load_t(kt + 2);
    }
    u16* xs = smem + (kt & 1) * 2560;
    u16* wsb = smem + 5120 + (kt & 1) * 7680;
    bf16x8 af[4], bfr[3];
#pragma unroll
    for (int rt = 0; rt < 4; ++rt)
      af[rt] = *(const bf16x8*)&xs[(rt * 16 + ln) * 40 + qd * 8];
#pragma unroll
    for (int ct = 0; ct < 3; ++ct)
      bfr[ct] = *(const bf16x8*)&wsb[(w * 48 + ct * 16 + ln) * 40 + qd * 8];
#pragma unroll
    for (int rt = 0; rt < 4; ++rt)
#pragma unroll
      for (int ct = 0; ct < 3; ++ct)
        acc[rt][ct] = __builtin_amdgcn_mfma_f32_16x16x32_bf16(
            af[rt], bfr[ct], acc[rt][ct], 0, 0, 0);
    __syncthreads();  // protects write_b(kt+2) into buf(kt&1) next iter
  }

  // epilogue (all compute done, barrier above): q,k direct; v via LDS transpose
  u16* vt = smem;  // 64*72 u16 reuse
#pragma unroll
  for (int ct = 0; ct < 3; ++ct) {
    int col = w * 48 + ct * 16 + ln;
    int mat = col >> 6, d = col & 63;
    if (mat < 2) {
      const float* bp = (mat == 0) ? bq : bk;
      u16* op = (mat == 0) ? qb : kb;
      float bias = bp[d];
      float scale = (mat == 0) ? 0.18033688011112042f : 1.0f;
#pragma unroll
      for (int rt = 0; rt < 4; ++rt)
#pragma unroll
        for (int r = 0; r < 4; ++r)
          op[(size_t)(row0 + rt * 16 + qd * 4 + r) * 64 + d] =
              f2b((acc[rt][ct][r] + bias) * scale);
    } else {
      float bias = bv[d];
#pragma unroll
      for (int rt = 0; rt < 4; ++rt)
#pragma unroll
        for (int r = 0; r < 4; ++r)
          vt[d * 72 + rt * 16 + qd * 4 + r] = f2b(acc[rt][ct][r] + bias);
    }
  }
  __syncthreads();
  {
    int d = tid >> 2, so = (tid & 3) * 16;
    int b = row0 >> 12, s0 = row0 & 4095;
    u16* dst = vbT + ((size_t)b * 64 + d) * 4096 + s0 + so;
    *(u16x8*)dst = *(const u16x8*)&vt[d * 72 + so];
    *(u16x8*)(dst + 8) = *(const u16x8*)&vt[d * 72 + so + 8];
  }
}

// ---------------------------------------------------------------------------
// Kernel 3: causal flash attention, BARRIER-FREE inner loop. Block = 128 q
// rows (32/wave), KV chunk <= 16 tiles of 64. K/V frags loaded direct
// global->reg (L2-resident per XCD via b=id&7). LDS only for P C->A layout.
// No running max (exp2 direct, fp32 partials combine linearly in comb_k).
// ---------------------------------------------------------------------------
__global__ __launch_bounds__(256, 3) void attn_k(const u16* __restrict__ qb,
                                                 const u16* __restrict__ kb,
                                                 const u16* __restrict__ vbT,
                                                 float* __restrict__ po,
                                                 float* __restrict__ pl) {
  __shared__ __align__(16) u16 ps[4 * 16 * 88];
  const int tid = threadIdx.x;
  const int w = tid >> 6, ln = tid & 15, qd = (tid >> 4) & 3;
  const int id = blockIdx.x;
  const int b = id & 7;
  int t = id >> 3;  // 0..79, qi descending (LPT-ish)
  int qi = 31, rem = t;
  for (;;) {
    int c = (2 * qi + 2 + 15) >> 4;
    if (rem < c) break;
    rem -= c;
    --qi;
  }
  const int chunk = rem;
  const int tstart = rem * 16;
  int tcount = 2 * qi + 2 - tstart;
  if (tcount > 16) tcount = 16;
  const int q0 = qi * 128;
  const int q0w = q0 + w * 32;
  const int base = b * S_;
  const u16* kg = kb + (size_t)base * 64;
  const u16* vg = vbT + (size_t)b * 64 * 4096;

  bf16x8 qf[2][2];
#pragma unroll
  for (int qt = 0; qt < 2; ++qt) {
    const u16* qrow = qb + (size_t)(base + q0w + qt * 16 + ln) * 64;
    qf[qt][0] = *(const bf16x8*)(qrow + qd * 8);
    qf[qt][1] = *(const bf16x8*)(qrow + 32 + qd * 8);
  }
  const f32x4 z4 = {0.f, 0.f, 0.f, 0.f};
  f32x4 o[2][4] = {{z4, z4, z4, z4}, {z4, z4, z4, z4}};
  float lp[2][4] = {{0.f, 0.f, 0.f, 0.f}, {0.f, 0.f, 0.f, 0.f}};
  u16* psw = ps + w * (16 * 88);

  for (int it = 0; it < tcount; ++it) {
    const int t0a = (tstart + it) * 64;
    // direct global->reg K and V fragments (L2 hits; no barrier, no staging)
    bf16x8 kf[2][4], vf[2][4];
#pragma unroll
    for (int kc = 0; kc < 2; ++kc)
#pragma unroll
      for (int nt = 0; nt < 4; ++nt) {
        kf[kc][nt] = *(const bf16x8*)(kg + (size_t)(t0a + nt * 16 + ln) * 64 +
                                      kc * 32 + qd * 8);
        vf[kc][nt] = *(const bf16x8*)(vg + (size_t)(nt * 16 + ln) * 4096 + t0a +
                                      kc * 32 + qd * 8);
      }
#pragma unroll
    for (int qt = 0; qt < 2; ++qt) {
      f32x4 s[4] = {z4, z4, z4, z4};
#pragma unroll
      for (int kc = 0; kc < 2; ++kc)
#pragma unroll
        for (int nt = 0; nt < 4; ++nt)
          s[nt] = __builtin_amdgcn_mfma_f32_16x16x32_bf16(qf[qt][kc], kf[kc][nt],
                                                          s[nt], 0, 0, 0);
      if (t0a >= q0) {  // diagonal region: causal mask
#pragma unroll
        for (int nt = 0; nt < 4; ++nt) {
          int tg = t0a + nt * 16 + ln;
#pragma unroll
          for (int r = 0; r < 4; ++r)
            if (tg > q0w + qt * 16 + qd * 4 + r) s[nt][r] = -INFINITY;
        }
      }
#pragma unroll
      for (int nt = 0; nt < 4; ++nt)
#pragma unroll
        for (int r = 0; r < 4; ++r) {
          float p = __builtin_amdgcn_exp2f(s[nt][r]);
          lp[qt][r] += p;
          psw[(qd * 4 + r) * 88 + nt * 16 + ln] = f2b(p);
        }
      // per-wave LDS roundtrip (C-layout -> A-layout); compiler orders lgkmcnt
#pragma unroll
      for (int kc = 0; kc < 2; ++kc) {
        bf16x8 afr = *(const bf16x8*)&psw[ln * 88 + kc * 32 + qd * 8];
#pragma unroll
        for (int nt = 0; nt < 4; ++nt)
          o[qt][nt] = __builtin_amdgcn_mfma_f32_16x16x32_bf16(afr, vf[kc][nt],
                                                              o[qt][nt], 0, 0, 0);
      }
    }
  }

  float* poc = po + (size_t)chunk * M_ * 64;
  float* plc = pl + (size_t)chunk * M_;
#pragma unroll
  for (int qt = 0; qt < 2; ++qt)
#pragma unroll
    for (int r = 0; r < 4; ++r) {
      float v = lp[qt][r];
      v += __shfl_xor(v, 1); v += __shfl_xor(v, 2);
      v += __shfl_xor(v, 4); v += __shfl_xor(v, 8);
      int row = base + q0w + qt * 16 + qd * 4 + r;
#pragma unroll
      for (int nt = 0; nt < 4; ++nt)
        poc[(size_t)row * 64 + nt * 16 + ln] = o[qt][nt][r];
      if (ln == 0) plc[row] = v;
    }
}

// ---------------------------------------------------------------------------
// Kernel 4: combine <=4 chunk partials: out = sum(o_c) / sum(l_c)
// ---------------------------------------------------------------------------
__global__ __launch_bounds__(256) void comb_k(const float* __restrict__ po,
                                              const float* __restrict__ pl,
                                              float* __restrict__ out) {
  int idx = blockIdx.x * 256 + threadIdx.x;  // 524288 threads
  int r = idx >> 4, d0 = (idx & 15) * 4;
  int qi = (r & 4095) >> 7;
  int nch = (2 * qi + 2 + 15) >> 4;
  float4 a = {0.f, 0.f, 0.f, 0.f};
  float l = 0.f;
  for (int c = 0; c < nch; ++c) {
    float4 p = *(const float4*)(po + (size_t)c * M_ * 64 + (size_t)r * 64 + d0);
    a.x += p.x; a.y += p.y; a.z += p.z; a.w += p.w;
    l += pl[(size_t)c * M_ + r];
  }
  float inv = 1.0f / l;
  a.x *= inv; a.y *= inv; a.z *= inv; a.w *= inv;
  *(float4*)(out + (size_t)r * 64 + d0) = a;
}

// ---------------------------------------------------------------------------
extern "C" void kernel_launch(void* const* d_in, const int* in_sizes, int n_in,
                              void* d_out, int out_size, void* d_ws, size_t ws_size,
                              hipStream_t stream) {
  const float* x  = (const float*)d_in[0];
  const float* Wq = (const float*)d_in[1];
  const float* bq = (const float*)d_in[2];
  const float* Wk = (const float*)d_in[3];
  const float* bk = (const float*)d_in[4];
  const float* Wv = (const float*)d_in[5];
  const float* bv = (const float*)d_in[6];
  float* out = (float*)d_out;

  char* wsp = (char*)d_ws;
  u16* WbT  = (u16*)wsp;                     //  294912 B
  u16* qb   = (u16*)(wsp + 294912);          // 4 MiB
  u16* kb   = (u16*)(wsp + 4489216);         // 4 MiB
  u16* vbT  = (u16*)(wsp + 8683520);         // 4 MiB  [b][d][s]
  float* po = (float*)(wsp + 12877824);      // 4 x 8 MiB chunk partials
  float* pl = (float*)(wsp + 46432256);      // 4 x 128 KiB

  hipLaunchKernelGGL(wconv_k, dim3(36), dim3(256), 0, stream, Wq, Wk, Wv, WbT);
  hipLaunchKernelGGL(qkv_k, dim3(512), dim3(256), 0, stream,
                     x, WbT, bq, bk, bv, qb, kb, vbT);
  hipLaunchKernelGGL(attn_k, dim3(640), dim3(256), 0, stream,
                     qb, kb, vbT, po, pl);
  hipLaunchKernelGGL(comb_k, dim3(2048), dim3(256), 0, stream, po, pl, out);
}

// Round 4
// 230.768 us; speedup vs baseline: 1.1662x; 1.1662x over previous
//
#include <hip/hip_runtime.h>

typedef unsigned short u16;
typedef __bf16 bf16_t;
typedef bf16_t bf16x8 __attribute__((ext_vector_type(8)));
typedef float f32x4 __attribute__((ext_vector_type(4)));
typedef u16 u16x8 __attribute__((ext_vector_type(8)));
typedef u16 u16x4 __attribute__((ext_vector_type(4)));

#define B_ 8
#define S_ 4096
#define H_ 768
#define M_ (B_ * S_)

// round-to-nearest-even fp32 -> bf16
__device__ __forceinline__ u16 f2b(float f) {
  unsigned u = __float_as_uint(f);
  u += 0x7fffu + ((u >> 16) & 1u);
  return (u16)(u >> 16);
}

// async global->LDS, 16B per lane; lds base must be wave-uniform
__device__ __forceinline__ void gl_lds16(const void* g, void* l) {
  __builtin_amdgcn_global_load_lds(
      (const __attribute__((address_space(1))) void*)g,
      (__attribute__((address_space(3))) void*)l, 16, 0, 0);
}

// ---------------------------------------------------------------------------
// Kernel 1: WbT[n][k] bf16 (n: 0-63=q,64-127=k,128-191=v). Coalesced.
// ---------------------------------------------------------------------------
__global__ __launch_bounds__(256) void wconv_k(const float* __restrict__ Wq,
                                               const float* __restrict__ Wk,
                                               const float* __restrict__ Wv,
                                               u16* __restrict__ WbT) {
  __shared__ float wt[64 * 68];
  const int tid = threadIdx.x;
  int mat = blockIdx.x / 12;
  int k0 = (blockIdx.x % 12) * 64;
  const float* W = (mat == 0) ? Wq : ((mat == 1) ? Wk : Wv);
  int r = tid >> 2, c0 = (tid & 3) * 16;
  const float* src = W + (size_t)(k0 + r) * 64 + c0;
#pragma unroll
  for (int j = 0; j < 16; j += 4)
    *(float4*)&wt[r * 68 + c0 + j] = *(const float4*)(src + j);
  __syncthreads();
  int d = tid >> 2;
  u16* dst = WbT + (size_t)(mat * 64 + d) * 768 + k0 + c0;
  u16x8 o0, o1;
#pragma unroll
  for (int j = 0; j < 8; ++j) o0[j] = f2b(wt[(c0 + j) * 68 + d]);
#pragma unroll
  for (int j = 0; j < 8; ++j) o1[j] = f2b(wt[(c0 + 8 + j) * 68 + d]);
  *(u16x8*)dst = o0;
  *(u16x8*)(dst + 8) = o1;
}

// ---------------------------------------------------------------------------
// Kernel 2: QKV projection (unchanged from R2 — HBM-bound-ish, known good).
// q pre-scaled by 0.125*log2(e). q,k stored [s][d]; V stored [b][d][s].
// ---------------------------------------------------------------------------
__global__ __launch_bounds__(256) void qkv_k(const float* __restrict__ x,
                                             const u16* __restrict__ WbT,
                                             const float* __restrict__ bq,
                                             const float* __restrict__ bk,
                                             const float* __restrict__ bv,
                                             u16* __restrict__ qb,
                                             u16* __restrict__ kb,
                                             u16* __restrict__ vbT) {
  __shared__ __align__(16) u16 smem[2 * 2560 + 2 * 7680];  // xs[2], ws[2]
  const int tid = threadIdx.x;
  const int w = tid >> 6, ln = tid & 15, qd = (tid >> 4) & 3;
  const int row0 = blockIdx.x * 64;

  const f32x4 z4 = {0.f, 0.f, 0.f, 0.f};
  f32x4 acc[4][3];
#pragma unroll
  for (int rt = 0; rt < 4; ++rt)
#pragma unroll
    for (int ct = 0; ct < 3; ++ct) acc[rt][ct] = z4;

  const int xr = tid >> 2, xc = (tid & 3) * 8;
  float4 xf0, xf1;
  u16x8 wf[3];

  auto load_t = [&](int kt) {
    const float* sx = x + (size_t)(row0 + xr) * 768 + kt * 32 + xc;
    xf0 = *(const float4*)sx;
    xf1 = *(const float4*)(sx + 4);
#pragma unroll
    for (int i = 0; i < 3; ++i) {
      int c = i * 256 + tid;
      int r = c >> 2, off = (c & 3) * 8;
      wf[i] = *(const u16x8*)(WbT + (size_t)r * 768 + kt * 32 + off);
    }
  };
  auto write_b = [&](int kt) {
    u16* xs = smem + (kt & 1) * 2560;
    u16* wsb = smem + 5120 + (kt & 1) * 7680;
    u16x8 v;
    v[0] = f2b(xf0.x); v[1] = f2b(xf0.y); v[2] = f2b(xf0.z); v[3] = f2b(xf0.w);
    v[4] = f2b(xf1.x); v[5] = f2b(xf1.y); v[6] = f2b(xf1.z); v[7] = f2b(xf1.w);
    *(u16x8*)&xs[xr * 40 + xc] = v;
#pragma unroll
    for (int i = 0; i < 3; ++i) {
      int c = i * 256 + tid;
      int r = c >> 2, off = (c & 3) * 8;
      *(u16x8*)&wsb[r * 40 + off] = wf[i];
    }
  };

  load_t(0);
  write_b(0);
  load_t(1);
  for (int kt = 0; kt < 24; ++kt) {
    __syncthreads();
    if (kt < 23) {
      write_b(kt + 1);
      if (kt < 22) load_t(kt + 2);
    }
    u16* xs = smem + (kt & 1) * 2560;
    u16* wsb = smem + 5120 + (kt & 1) * 7680;
    bf16x8 af[4], bfr[3];
#pragma unroll
    for (int rt = 0; rt < 4; ++rt)
      af[rt] = *(const bf16x8*)&xs[(rt * 16 + ln) * 40 + qd * 8];
#pragma unroll
    for (int ct = 0; ct < 3; ++ct)
      bfr[ct] = *(const bf16x8*)&wsb[(w * 48 + ct * 16 + ln) * 40 + qd * 8];
#pragma unroll
    for (int rt = 0; rt < 4; ++rt)
#pragma unroll
      for (int ct = 0; ct < 3; ++ct)
        acc[rt][ct] = __builtin_amdgcn_mfma_f32_16x16x32_bf16(
            af[rt], bfr[ct], acc[rt][ct], 0, 0, 0);
    __syncthreads();
  }

  u16* vt = smem;  // 64*72 u16 reuse
#pragma unroll
  for (int ct = 0; ct < 3; ++ct) {
    int col = w * 48 + ct * 16 + ln;
    int mat = col >> 6, d = col & 63;
    if (mat < 2) {
      const float* bp = (mat == 0) ? bq : bk;
      u16* op = (mat == 0) ? qb : kb;
      float bias = bp[d];
      float scale = (mat == 0) ? 0.18033688011112042f : 1.0f;
#pragma unroll
      for (int rt = 0; rt < 4; ++rt)
#pragma unroll
        for (int r = 0; r < 4; ++r)
          op[(size_t)(row0 + rt * 16 + qd * 4 + r) * 64 + d] =
              f2b((acc[rt][ct][r] + bias) * scale);
    } else {
      float bias = bv[d];
#pragma unroll
      for (int rt = 0; rt < 4; ++rt)
#pragma unroll
        for (int r = 0; r < 4; ++r)
          vt[d * 72 + rt * 16 + qd * 4 + r] = f2b(acc[rt][ct][r] + bias);
    }
  }
  __syncthreads();
  {
    int d = tid >> 2, so = (tid & 3) * 16;
    int b = row0 >> 12, s0 = row0 & 4095;
    u16* dst = vbT + ((size_t)b * 64 + d) * 4096 + s0 + so;
    *(u16x8*)dst = *(const u16x8*)&vt[d * 72 + so];
    *(u16x8*)(dst + 8) = *(const u16x8*)&vt[d * 72 + so + 8];
  }
}

// ---------------------------------------------------------------------------
// Kernel 3: causal flash attention. Block = 256 q rows (64/wave, qt=4),
// KV chunks of <=8 64-wide tiles (576 blocks). Staged K/V double-buffered via
// global_load_lds, 1 barrier/iter. Swapped operands: S^T = K·Q^T so P staging
// is 4x ds_write_b64 + 2x ds_read_b128 per qt; PV as O^T = V^T·P^T.
// No running max; bf16 partials combine linearly in comb_k.
// ---------------------------------------------------------------------------
__global__ __launch_bounds__(256, 2) void attn_k(const u16* __restrict__ qb,
                                                 const u16* __restrict__ kb,
                                                 const u16* __restrict__ vbT,
                                                 u16* __restrict__ po,
                                                 float* __restrict__ pl) {
  __shared__ __align__(16) u16 ks[2][4096];   // [t][d] swizzled
  __shared__ __align__(16) u16 vs[2][4096];   // [d][t] swizzled
  __shared__ __align__(16) u16 ps[4 * 16 * 72];  // per-wave P [q][t](+pad)
  const int tid = threadIdx.x;
  const int w = tid >> 6, ln = tid & 15, qd = (tid >> 4) & 3;
  const int id = blockIdx.x;
  const int b = id & 7;
  int t = id >> 3;  // 0..71, qi descending (LPT)
  int qi = 15, rem = t;
  for (;;) {
    int c = (4 * qi + 11) >> 3;  // ceil((4qi+4)/8) chunks for this qi
    if (rem < c) break;
    rem -= c;
    --qi;
  }
  const int chunk = rem;
  const int tstart = rem * 8;
  int tcount = 4 * qi + 4 - tstart;
  if (tcount > 8) tcount = 8;
  const int q0 = qi * 256, q0w = q0 + w * 64;
  const int base = b * S_;
  const u16* kg = kb + (size_t)base * 64;
  const u16* vg = vbT + (size_t)b * 64 * 4096;

  bf16x8 qf[4][2];  // Q^T B-frags == Q A-frags: lane holds Q[q=..+ln][d 8]
#pragma unroll
  for (int qt = 0; qt < 4; ++qt) {
    const u16* qrow = qb + (size_t)(base + q0w + qt * 16 + ln) * 64;
    qf[qt][0] = *(const bf16x8*)(qrow + qd * 8);
    qf[qt][1] = *(const bf16x8*)(qrow + 32 + qd * 8);
  }
  const f32x4 z4 = {0.f, 0.f, 0.f, 0.f};
  f32x4 o[4][4];  // O^T C-layout: o[qt][ntd][r] = O^T[d=ntd*16+qd*4+r][q=..ln]
#pragma unroll
  for (int qt = 0; qt < 4; ++qt)
#pragma unroll
    for (int nt = 0; nt < 4; ++nt) o[qt][nt] = z4;
  float lp[4] = {0.f, 0.f, 0.f, 0.f};
  u16* psw = ps + w * (16 * 72);
  const int lr = (tid & 63) >> 3, csl = tid & 7;

  auto prefetch = [&](int bufi, int tile) {
    const u16* kt_ = kg + (size_t)tile * 4096;
    const u16* vt_ = vg + tile * 64;
#pragma unroll
    for (int i = 0; i < 2; ++i) {
      int r0 = w * 16 + i * 8;
      int r = r0 + lr;
      int c = csl ^ (r & 7);
      gl_lds16(kt_ + r * 64 + c * 8, &ks[bufi][r0 * 64]);
      gl_lds16(vt_ + (size_t)r * 4096 + c * 8, &vs[bufi][r0 * 64]);
    }
  };

  prefetch(0, tstart);
  int buf = 0;
  for (int it = 0; it < tcount; ++it) {
    __syncthreads();  // drains prefetch vmcnt; protects buffer reuse
    if (it + 1 < tcount) prefetch(buf ^ 1, tstart + it + 1);
    const int t0a = (tstart + it) * 64;

    // K A-frags and V^T A-frags, register-resident, reused across 4 qt
    bf16x8 kf[2][4], vf[2][4];
#pragma unroll
    for (int kc = 0; kc < 2; ++kc) {
      int cs = ((kc * 4 + qd) ^ (ln & 7)) * 8;
#pragma unroll
      for (int nt = 0; nt < 4; ++nt) {
        kf[kc][nt] = *(const bf16x8*)&ks[buf][(nt * 16 + ln) * 64 + cs];
        vf[kc][nt] = *(const bf16x8*)&vs[buf][(nt * 16 + ln) * 64 + cs];
      }
    }
#pragma unroll
    for (int qt = 0; qt < 4; ++qt) {
      // S^T[t][q]: lane holds col q=ln, rows t = t0a + nt*16 + qd*4 + r
      f32x4 s[4] = {z4, z4, z4, z4};
#pragma unroll
      for (int kc = 0; kc < 2; ++kc)
#pragma unroll
        for (int nt = 0; nt < 4; ++nt)
          s[nt] = __builtin_amdgcn_mfma_f32_16x16x32_bf16(kf[kc][nt], qf[qt][kc],
                                                          s[nt], 0, 0, 0);
      if (t0a + 63 > q0w + qt * 16) {  // tile overlaps/past diagonal for these q
#pragma unroll
        for (int nt = 0; nt < 4; ++nt) {
          int tg = t0a + nt * 16 + qd * 4;
          int qg = q0w + qt * 16 + ln;
#pragma unroll
          for (int r = 0; r < 4; ++r)
            if (tg + r > qg) s[nt][r] = -INFINITY;
        }
      }
      // exp2 + packed b64 P-write (pst[q=ln][t])
#pragma unroll
      for (int nt = 0; nt < 4; ++nt) {
        u16x4 pk;
#pragma unroll
        for (int r = 0; r < 4; ++r) {
          float p = __builtin_amdgcn_exp2f(s[nt][r]);
          lp[qt] += p;
          pk[r] = f2b(p);
        }
        *(u16x4*)&psw[ln * 72 + nt * 16 + qd * 4] = pk;
      }
      // O^T += V^T · P^T : P^T B-frag is one b128 per kc
#pragma unroll
      for (int kc = 0; kc < 2; ++kc) {
        bf16x8 pf = *(const bf16x8*)&psw[ln * 72 + kc * 32 + qd * 8];
#pragma unroll
        for (int nt = 0; nt < 4; ++nt)
          o[qt][nt] = __builtin_amdgcn_mfma_f32_16x16x32_bf16(vf[kc][nt], pf,
                                                              o[qt][nt], 0, 0, 0);
      }
    }
    buf ^= 1;
  }

  // epilogue: lp reduce (q on lanes -> xor over qd bits), packed bf16 stores
  u16* poc = po + (size_t)chunk * M_ * 64;
  float* plc = pl + (size_t)chunk * M_;
#pragma unroll
  for (int qt = 0; qt < 4; ++qt) {
    float v = lp[qt];
    v += __shfl_xor(v, 16);
    v += __shfl_xor(v, 32);
    int row = base + q0w + qt * 16 + ln;
#pragma unroll
    for (int nt = 0; nt < 4; ++nt) {
      u16x4 ov;
#pragma unroll
      for (int r = 0; r < 4; ++r) ov[r] = f2b(o[qt][nt][r]);
      *(u16x4*)&poc[(size_t)row * 64 + nt * 16 + qd * 4] = ov;
    }
    if (qd == 0) plc[row] = v;
  }
}

// ---------------------------------------------------------------------------
// Kernel 4: combine <=8 chunk partials: out = sum(o_c) / sum(l_c)
// ---------------------------------------------------------------------------
__global__ __launch_bounds__(256) void comb_k(const u16* __restrict__ po,
                                              const float* __restrict__ pl,
                                              float* __restrict__ out) {
  int idx = blockIdx.x * 256 + threadIdx.x;  // 524288 threads
  int r = idx >> 4, d0 = (idx & 15) * 4;
  int qi = (r & 4095) >> 8;
  int nch = (4 * qi + 11) >> 3;
  float4 a = {0.f, 0.f, 0.f, 0.f};
  float l = 0.f;
  for (int c = 0; c < nch; ++c) {
    u16x4 p = *(const u16x4*)(po + ((size_t)c * M_ + r) * 64 + d0);
    a.x += __uint_as_float((unsigned)p[0] << 16);
    a.y += __uint_as_float((unsigned)p[1] << 16);
    a.z += __uint_as_float((unsigned)p[2] << 16);
    a.w += __uint_as_float((unsigned)p[3] << 16);
    l += pl[(size_t)c * M_ + r];
  }
  float inv = 1.0f / l;
  a.x *= inv; a.y *= inv; a.z *= inv; a.w *= inv;
  *(float4*)(out + (size_t)r * 64 + d0) = a;
}

// ---------------------------------------------------------------------------
extern "C" void kernel_launch(void* const* d_in, const int* in_sizes, int n_in,
                              void* d_out, int out_size, void* d_ws, size_t ws_size,
                              hipStream_t stream) {
  const float* x  = (const float*)d_in[0];
  const float* Wq = (const float*)d_in[1];
  const float* bq = (const float*)d_in[2];
  const float* Wk = (const float*)d_in[3];
  const float* bk = (const float*)d_in[4];
  const float* Wv = (const float*)d_in[5];
  const float* bv = (const float*)d_in[6];
  float* out = (float*)d_out;

  char* wsp = (char*)d_ws;
  u16* WbT  = (u16*)wsp;                     //  294912 B
  u16* qb   = (u16*)(wsp + 294912);          // 4 MiB
  u16* kb   = (u16*)(wsp + 4489216);         // 4 MiB
  u16* vbT  = (u16*)(wsp + 8683520);         // 4 MiB  [b][d][s]
  u16* po   = (u16*)(wsp + 12877824);        // 8 x 4 MiB bf16 chunk partials
  float* pl = (float*)(wsp + 46432256);      // 8 x 128 KiB fp32 l partials

  hipLaunchKernelGGL(wconv_k, dim3(36), dim3(256), 0, stream, Wq, Wk, Wv, WbT);
  hipLaunchKernelGGL(qkv_k, dim3(512), dim3(256), 0, stream,
                     x, WbT, bq, bk, bv, qb, kb, vbT);
  hipLaunchKernelGGL(attn_k, dim3(576), dim3(256), 0, stream,
                     qb, kb, vbT, po, pl);
  hipLaunchKernelGGL(comb_k, dim3(2048), dim3(256), 0, stream, po, pl, out);
}